// Round 1
// baseline (581.807 us; speedup 1.0000x reference)
//
#include <hip/hip_runtime.h>
#include <hip/hip_bf16.h>
#include <math.h>

#define T_SEQ   2048
#define D_MOD   1024
#define N_HEADS 16
#define HEAD_DIM 64
#define B_BATCH 2
#define M_ROWS  (B_BATCH * T_SEQ)   // 4096

typedef unsigned short u16;
typedef __attribute__((ext_vector_type(8))) short short8;
typedef __attribute__((ext_vector_type(4))) float floatx4;

__device__ inline floatx4 mfma16(short8 a, short8 b, floatx4 c) {
  return __builtin_amdgcn_mfma_f32_16x16x32_bf16(a, b, c, 0, 0, 0);
}

__device__ inline u16 f2bf(float f) {
  __hip_bfloat16 h = __float2bfloat16(f);   // RTN
  return __builtin_bit_cast(u16, h);
}
__device__ inline float bf2f(u16 u) {
  unsigned int x = ((unsigned int)u) << 16;
  return __builtin_bit_cast(float, x);
}

// ---------------------------------------------------------------- casts
__global__ void cast_f32_to_bf16(const float* __restrict__ in, u16* __restrict__ out, int n) {
  int i = (blockIdx.x * blockDim.x + threadIdx.x) * 4;
  if (i >= n) return;
  float4 v = *(const float4*)(in + i);
  ushort4 o;
  o.x = f2bf(v.x); o.y = f2bf(v.y); o.z = f2bf(v.z); o.w = f2bf(v.w);
  *(ushort4*)(out + i) = o;
}

// ---------------------------------------------------------------- rope table (double precision, tiny)
__global__ void rope_table_kernel(float* __restrict__ cosT, float* __restrict__ sinT) {
  int tid = blockIdx.x * blockDim.x + threadIdx.x;   // T*32
  int t = tid >> 5, j = tid & 31;
  double inv = pow(10000.0, -((double)(2 * j) / 64.0));
  double a = (double)t * inv;
  cosT[tid] = (float)cos(a);
  sinT[tid] = (float)sin(a);
}

// ---------------------------------------------------------------- rope apply (in-place, bf16)
__global__ void rope_apply_kernel(u16* __restrict__ X, const float* __restrict__ cosT,
                                  const float* __restrict__ sinT) {
  int tid = blockIdx.x * blockDim.x + threadIdx.x;   // B*T*H*4
  int q8 = tid & 3;
  int h  = (tid >> 2) & 15;
  int bt = tid >> 6;                 // b*T + t
  int t  = bt & (T_SEQ - 1);
  size_t base = (size_t)bt * D_MOD + h * HEAD_DIM + q8 * 8;
  short8 x1 = *(short8*)(X + base);
  short8 x2 = *(short8*)(X + base + 32);
  const float* cp = cosT + t * 32 + q8 * 8;
  const float* sp = sinT + t * 32 + q8 * 8;
  short8 o1, o2;
#pragma unroll
  for (int i = 0; i < 8; ++i) {
    float f1 = bf2f((u16)x1[i]);
    float f2 = bf2f((u16)x2[i]);
    float c = cp[i], s = sp[i];
    o1[i] = (short)f2bf(f1 * c - f2 * s);
    o2[i] = (short)f2bf(f1 * s + f2 * c);
  }
  *(short8*)(X + base) = o1;
  *(short8*)(X + base + 32) = o2;
}

// ---------------------------------------------------------------- GEMM: C[M,N] = A[M,K] * Bw[N,K]^T + bias
// 64x64 tile / block, 4 waves, each wave 16 rows x 64 cols, direct global fragment loads.
template<int OUT_BF16>
__global__ __launch_bounds__(256) void gemm_bt_kernel(const u16* __restrict__ A, const u16* __restrict__ Bw,
                                                      const float* __restrict__ bias, void* __restrict__ Cv,
                                                      int M, int N, int K) {
  const int tid = threadIdx.x;
  const int w = tid >> 6, lane = tid & 63;
  const int g = lane >> 4, ln = lane & 15;
  const int m0 = blockIdx.y * 64 + w * 16;
  const int n0 = blockIdx.x * 64;
  const int ks8 = K >> 3;                     // row stride in short8 units
  const short8* ap  = (const short8*)(A + (size_t)(m0 + ln) * K);
  const short8* bp0 = (const short8*)(Bw + (size_t)(n0 + ln) * K);
  const short8* bp1 = bp0 + 16 * ks8;
  const short8* bp2 = bp0 + 32 * ks8;
  const short8* bp3 = bp0 + 48 * ks8;

  floatx4 acc[4];
#pragma unroll
  for (int nt = 0; nt < 4; ++nt) acc[nt] = (floatx4){0.f, 0.f, 0.f, 0.f};

  for (int k8 = 0; k8 < ks8; k8 += 4) {       // K step 32
    short8 a = ap[k8 + g];
    acc[0] = mfma16(a, bp0[k8 + g], acc[0]);
    acc[1] = mfma16(a, bp1[k8 + g], acc[1]);
    acc[2] = mfma16(a, bp2[k8 + g], acc[2]);
    acc[3] = mfma16(a, bp3[k8 + g], acc[3]);
  }

#pragma unroll
  for (int nt = 0; nt < 4; ++nt) {
    int n = n0 + nt * 16 + ln;
    float bv = bias[n];
#pragma unroll
    for (int r = 0; r < 4; ++r) {
      int m = m0 + g * 4 + r;
      float v = acc[nt][r] + bv;
      if (OUT_BF16) ((u16*)Cv)[(size_t)m * N + n] = f2bf(v);
      else          ((float*)Cv)[(size_t)m * N + n] = v;
    }
  }
}

// ---------------------------------------------------------------- flash attention (causal)
// Block: 64 q rows (4 waves x 16), KV tiles of 64. bf16 MFMA, fp32 online softmax.
__global__ __launch_bounds__(256) void flash_attn_kernel(const u16* __restrict__ Q, const u16* __restrict__ Kb,
                                                         const u16* __restrict__ V, u16* __restrict__ O) {
  // V^T tile: rows d (0..63), stride 144B, 16B chunk-XOR swizzle: chunk' = (k>>3) ^ (d>>3)
  __shared__ __align__(16) char vt[64 * 144];        // 9216 B
  __shared__ __align__(16) char pl[4][16 * 144];     // 9216 B  (per-wave P slab, stride 144B)
  const int tid = threadIdx.x;
  const int w = tid >> 6, lane = tid & 63;
  const int g = lane >> 4, ln = lane & 15;
  const int qt = blockIdx.x;
  const int bh = blockIdx.y;
  const int b = bh >> 4, h = bh & 15;
  const int q0 = qt * 64;
  const size_t rowbase = (size_t)b * T_SEQ * D_MOD + h * HEAD_DIM;

  // Q fragments, registers for the whole kernel
  short8 qf0, qf1;
  {
    const short8* qp = (const short8*)(Q + rowbase + (size_t)(q0 + w * 16 + ln) * D_MOD);
    qf0 = qp[g];
    qf1 = qp[4 + g];
  }
  floatx4 oacc[4];
#pragma unroll
  for (int nt = 0; nt < 4; ++nt) oacc[nt] = (floatx4){0.f, 0.f, 0.f, 0.f};
  float m_r[4] = {-INFINITY, -INFINITY, -INFINITY, -INFINITY};
  float l_r[4] = {0.f, 0.f, 0.f, 0.f};

  const int nkv = qt + 1;
  for (int kt = 0; kt < nkv; ++kt) {
    const int k0 = kt * 64;
    __syncthreads();   // protect vt/pl from previous iteration's readers
    // ---- stage V tile transposed into LDS (conflict-free swizzle)
#pragma unroll
    for (int p = 0; p < 2; ++p) {
      const int krow = (tid >> 3) + p * 32;
      const int d0 = (tid & 7) * 8;
      short8 vv = *(const short8*)(V + rowbase + (size_t)(k0 + krow) * D_MOD + d0);
#pragma unroll
      for (int i = 0; i < 8; ++i) {
        const int d = d0 + i;
        const int off = d * 144 + ((((krow >> 3) ^ (d >> 3)) & 7) << 4) + ((krow & 7) << 1);
        *(u16*)(vt + off) = (u16)vv[i];
      }
    }
    // ---- S = Q K^T (K fragments direct from global)
    float sv[4][4];
    const bool diag = (kt == qt);
#pragma unroll
    for (int nt = 0; nt < 4; ++nt) {
      floatx4 s = (floatx4){0.f, 0.f, 0.f, 0.f};
      const short8* kp = (const short8*)(Kb + rowbase + (size_t)(k0 + nt * 16 + ln) * D_MOD);
      s = mfma16(qf0, kp[g], s);
      s = mfma16(qf1, kp[4 + g], s);
#pragma unroll
      for (int r = 0; r < 4; ++r) {
        float x = s[r] * 0.125f;
        if (diag && (nt * 16 + ln) > (w * 16 + g * 4 + r)) x = -10000.0f;  // matches ref clamp(-inf)
        sv[nt][r] = x;
      }
    }
    // ---- online softmax (rows live in 16-lane groups; reduce via shfl_xor 1,2,4,8)
#pragma unroll
    for (int r = 0; r < 4; ++r) {
      float mx = fmaxf(fmaxf(sv[0][r], sv[1][r]), fmaxf(sv[2][r], sv[3][r]));
      mx = fmaxf(mx, __shfl_xor(mx, 1));
      mx = fmaxf(mx, __shfl_xor(mx, 2));
      mx = fmaxf(mx, __shfl_xor(mx, 4));
      mx = fmaxf(mx, __shfl_xor(mx, 8));
      float mnew = fmaxf(m_r[r], mx);
      float alpha = __expf(m_r[r] - mnew);   // first tile: exp(-inf)=0
      float ssum = 0.f;
#pragma unroll
      for (int nt = 0; nt < 4; ++nt) {
        float pv = __expf(sv[nt][r] - mnew);
        sv[nt][r] = pv;
        ssum += pv;
      }
      ssum += __shfl_xor(ssum, 1);
      ssum += __shfl_xor(ssum, 2);
      ssum += __shfl_xor(ssum, 4);
      ssum += __shfl_xor(ssum, 8);
      l_r[r] = l_r[r] * alpha + ssum;
      m_r[r] = mnew;
#pragma unroll
      for (int nt = 0; nt < 4; ++nt) oacc[nt][r] *= alpha;
    }
    // ---- P -> bf16 -> LDS (C-layout write, A-layout read)
    char* pb = pl[w];
#pragma unroll
    for (int nt = 0; nt < 4; ++nt)
#pragma unroll
      for (int r = 0; r < 4; ++r)
        *(u16*)(pb + (g * 4 + r) * 144 + (nt * 16 + ln) * 2) = f2bf(sv[nt][r]);
    __syncthreads();   // vt + pl ready
    // ---- O += P V
#pragma unroll
    for (int ks = 0; ks < 2; ++ks) {
      short8 pa = *(const short8*)(pb + ln * 144 + (ks * 32 + g * 8) * 2);
#pragma unroll
      for (int nt = 0; nt < 4; ++nt) {
        const int d = nt * 16 + ln;
        const int kc = ks * 4 + g;                       // 16B chunk index along k
        short8 vb = *(const short8*)(vt + d * 144 + (((kc ^ (d >> 3)) & 7) << 4));
        oacc[nt] = mfma16(pa, vb, oacc[nt]);
      }
    }
  }
  // ---- epilogue: O / l, store bf16 [B,T,D]
#pragma unroll
  for (int r = 0; r < 4; ++r) {
    float inv = 1.0f / l_r[r];
    const int q = q0 + w * 16 + g * 4 + r;
    u16* op = O + rowbase + (size_t)q * D_MOD;
#pragma unroll
    for (int nt = 0; nt < 4; ++nt)
      op[nt * 16 + ln] = f2bf(oacc[nt][r] * inv);
  }
}

// ---------------------------------------------------------------- launch
extern "C" void kernel_launch(void* const* d_in, const int* in_sizes, int n_in,
                              void* d_out, int out_size, void* d_ws, size_t ws_size,
                              hipStream_t stream) {
  const float* x  = (const float*)d_in[0];
  // d_in[1] = causal_mask (unused; causality computed analytically)
  const float* Wq = (const float*)d_in[2];
  const float* bq = (const float*)d_in[3];
  const float* Wk = (const float*)d_in[4];
  const float* bk = (const float*)d_in[5];
  const float* Wv = (const float*)d_in[6];
  const float* bv = (const float*)d_in[7];
  const float* Wo = (const float*)d_in[8];
  const float* bo = (const float*)d_in[9];
  float* out = (float*)d_out;

  char* ws = (char*)d_ws;
  const size_t MB = 1024 * 1024;
  u16* Xb   = (u16*)(ws + 0);          // 8 MB   [4096,1024] bf16
  u16* Wqb  = (u16*)(ws + 8 * MB);     // 2 MB
  u16* Wkb  = (u16*)(ws + 10 * MB);
  u16* Wvb  = (u16*)(ws + 12 * MB);
  u16* Wob  = (u16*)(ws + 14 * MB);
  u16* Qb   = (u16*)(ws + 16 * MB);    // 8 MB each
  u16* Kb   = (u16*)(ws + 24 * MB);
  u16* Vb   = (u16*)(ws + 32 * MB);
  u16* Ab   = (u16*)(ws + 40 * MB);    // attention output bf16
  float* cosT = (float*)(ws + 48 * MB);          // 256 KB
  float* sinT = (float*)(ws + 48 * MB + 256 * 1024);

  const int NX = M_ROWS * D_MOD;   // 4194304
  const int NW = D_MOD * D_MOD;    // 1048576
  cast_f32_to_bf16<<<NX / 1024, 256, 0, stream>>>(x, Xb, NX);
  cast_f32_to_bf16<<<NW / 1024, 256, 0, stream>>>(Wq, Wqb, NW);
  cast_f32_to_bf16<<<NW / 1024, 256, 0, stream>>>(Wk, Wkb, NW);
  cast_f32_to_bf16<<<NW / 1024, 256, 0, stream>>>(Wv, Wvb, NW);
  cast_f32_to_bf16<<<NW / 1024, 256, 0, stream>>>(Wo, Wob, NW);
  rope_table_kernel<<<(T_SEQ * 32) / 256, 256, 0, stream>>>(cosT, sinT);

  dim3 ggrid(D_MOD / 64, M_ROWS / 64);   // (16, 64)
  gemm_bt_kernel<1><<<ggrid, 256, 0, stream>>>(Xb, Wqb, bq, Qb, M_ROWS, D_MOD, D_MOD);
  gemm_bt_kernel<1><<<ggrid, 256, 0, stream>>>(Xb, Wkb, bk, Kb, M_ROWS, D_MOD, D_MOD);
  gemm_bt_kernel<1><<<ggrid, 256, 0, stream>>>(Xb, Wvb, bv, Vb, M_ROWS, D_MOD, D_MOD);

  const int nrope = B_BATCH * T_SEQ * N_HEADS * 4;   // 262144
  rope_apply_kernel<<<nrope / 256, 256, 0, stream>>>(Qb, cosT, sinT);
  rope_apply_kernel<<<nrope / 256, 256, 0, stream>>>(Kb, cosT, sinT);

  dim3 fgrid(T_SEQ / 64, B_BATCH * N_HEADS);   // (32, 32)
  flash_attn_kernel<<<fgrid, 256, 0, stream>>>(Qb, Kb, Vb, Ab);

  gemm_bt_kernel<0><<<ggrid, 256, 0, stream>>>(Ab, Wob, bo, out, M_ROWS, D_MOD, D_MOD);
}

// Round 2
// 339.958 us; speedup vs baseline: 1.7114x; 1.7114x over previous
//
#include <hip/hip_runtime.h>
#include <hip/hip_bf16.h>
#include <math.h>

#define T_SEQ   2048
#define D_MOD   1024
#define N_HEADS 16
#define HEAD_DIM 64
#define B_BATCH 2
#define M_ROWS  (B_BATCH * T_SEQ)   // 4096

typedef unsigned short u16;
typedef __attribute__((ext_vector_type(8))) short short8;
typedef __attribute__((ext_vector_type(4))) float floatx4;

__device__ inline floatx4 mfma16(short8 a, short8 b, floatx4 c) {
  return __builtin_amdgcn_mfma_f32_16x16x32_bf16(a, b, c, 0, 0, 0);
}

__device__ inline u16 f2bf(float f) {
  __hip_bfloat16 h = __float2bfloat16(f);   // RTN
  return __builtin_bit_cast(u16, h);
}
__device__ inline float bf2f(u16 u) {
  unsigned int x = ((unsigned int)u) << 16;
  return __builtin_bit_cast(float, x);
}

// async global -> LDS, 16B per lane; dest = uniform base + lane*16
__device__ inline void gload16(const void* g, void* s) {
  __builtin_amdgcn_global_load_lds(
      (const __attribute__((address_space(1))) void*)g,
      (__attribute__((address_space(3))) void*)s, 16, 0, 0);
}

// ---------------------------------------------------------------- fused casts
// segments (in 1M-element units): [0,4)=x, 4=Wq, 5=Wk, 6=Wv, 7=Wo
__global__ void cast_all_kernel(const float* __restrict__ x,
                                const float* __restrict__ Wq, const float* __restrict__ Wk,
                                const float* __restrict__ Wv, const float* __restrict__ Wo,
                                u16* __restrict__ Xb, u16* __restrict__ Wqb, u16* __restrict__ Wkb,
                                u16* __restrict__ Wvb, u16* __restrict__ Wob) {
  size_t i4 = ((size_t)blockIdx.x * 256 + threadIdx.x) * 4;
  size_t seg = i4 >> 20;
  const float* src; u16* dst; size_t off;
  if (seg < 4)       { src = x;  dst = Xb;  off = i4; }
  else if (seg == 4) { src = Wq; dst = Wqb; off = i4 - ((size_t)4 << 20); }
  else if (seg == 5) { src = Wk; dst = Wkb; off = i4 - ((size_t)5 << 20); }
  else if (seg == 6) { src = Wv; dst = Wvb; off = i4 - ((size_t)6 << 20); }
  else               { src = Wo; dst = Wob; off = i4 - ((size_t)7 << 20); }
  float4 v = *(const float4*)(src + off);
  ushort4 o;
  o.x = f2bf(v.x); o.y = f2bf(v.y); o.z = f2bf(v.z); o.w = f2bf(v.w);
  *(ushort4*)(dst + off) = o;
}

// ---------------------------------------------------------------- rope table (double precision, tiny)
__global__ void rope_table_kernel(float* __restrict__ cosT, float* __restrict__ sinT) {
  int tid = blockIdx.x * blockDim.x + threadIdx.x;   // T*32
  int t = tid >> 5, j = tid & 31;
  double inv = pow(10000.0, -((double)(2 * j) / 64.0));
  double a = (double)t * inv;
  cosT[tid] = (float)cos(a);
  sinT[tid] = (float)sin(a);
}

// ---------------------------------------------------------------- GEMM: C[M,N] = A[M,K] * W[N,K]^T + bias
// 128x128 tile, BK=32, double-buffered LDS via global_load_lds(16B), 4 waves (2x2),
// each wave 64x64 output (acc[4][4]). Optional fused RoPE for z<2 (Q,K projections).
template<int OUT_BF16, int DO_ROPE>
__global__ __launch_bounds__(256) void gemm128_kernel(
    const u16* __restrict__ A,
    const u16* __restrict__ W0, const u16* __restrict__ W1, const u16* __restrict__ W2,
    const float* __restrict__ b0, const float* __restrict__ b1, const float* __restrict__ b2,
    void* __restrict__ C0, void* __restrict__ C1, void* __restrict__ C2,
    const float* __restrict__ cosT, const float* __restrict__ sinT) {
  const int z = blockIdx.z;
  const u16*  W    = (z == 0) ? W0 : (z == 1 ? W1 : W2);
  const float* bias = (z == 0) ? b0 : (z == 1 ? b1 : b2);
  void*       C    = (z == 0) ? C0 : (z == 1 ? C1 : C2);
  const int K = D_MOD, N = D_MOD;

  __shared__ __align__(16) u16 lA[2][128 * 32];   // 8KB each
  __shared__ __align__(16) u16 lB[2][128 * 32];

  const int tid = threadIdx.x;
  const int w = tid >> 6, l = tid & 63, g = l >> 4, ln = l & 15;
  const int wr = w >> 1, wc = w & 1;
  const int m0 = blockIdx.y * 128, n0 = blockIdx.x * 128;

  floatx4 acc[4][4];
#pragma unroll
  for (int mi = 0; mi < 4; ++mi)
#pragma unroll
    for (int ni = 0; ni < 4; ++ni) acc[mi][ni] = (floatx4){0.f, 0.f, 0.f, 0.f};

  // stage one 128x32 A-tile + B-tile into buf (512 chunks each, 2 per thread each)
  auto stage = [&](int buf, int kk) {
#pragma unroll
    for (int p = 0; p < 2; ++p) {
      int c = p * 256 + w * 64 + l;
      int r = c >> 2, cc = c & 3;
      gload16(A + (size_t)(m0 + r) * K + kk + cc * 8, &lA[buf][(p * 256 + w * 64) * 8]);
      gload16(W + (size_t)(n0 + r) * K + kk + cc * 8, &lB[buf][(p * 256 + w * 64) * 8]);
    }
  };

  stage(0, 0);
  __syncthreads();
  int cur = 0;
  for (int t = 0; t < K / 32; ++t) {
    if (t + 1 < K / 32) stage(cur ^ 1, (t + 1) * 32);
    short8 af[4], bf[4];
#pragma unroll
    for (int mi = 0; mi < 4; ++mi)
      af[mi] = *(const short8*)&lA[cur][(wr * 64 + mi * 16 + ln) * 32 + g * 8];
#pragma unroll
    for (int ni = 0; ni < 4; ++ni)
      bf[ni] = *(const short8*)&lB[cur][(wc * 64 + ni * 16 + ln) * 32 + g * 8];
#pragma unroll
    for (int mi = 0; mi < 4; ++mi)
#pragma unroll
      for (int ni = 0; ni < 4; ++ni)
        acc[mi][ni] = mfma16(af[mi], bf[ni], acc[mi][ni]);
    __syncthreads();   // drains vmcnt (next stage) + all LDS reads of cur
    cur ^= 1;
  }

  float bv[4];
#pragma unroll
  for (int ni = 0; ni < 4; ++ni) bv[ni] = bias[n0 + wc * 64 + ni * 16 + ln];

#pragma unroll
  for (int mi = 0; mi < 4; ++mi) {
#pragma unroll
    for (int r = 0; r < 4; ++r) {
      const int m = m0 + wr * 64 + mi * 16 + g * 4 + r;
      if (DO_ROPE && z < 2) {
        const int t = m & (T_SEQ - 1);
#pragma unroll
        for (int ni = 0; ni < 2; ++ni) {
          const int j = ni * 16 + ln;
          float cv = cosT[t * 32 + j], sv = sinT[t * 32 + j];
          float v1 = acc[mi][ni][r] + bv[ni];
          float v2 = acc[mi][ni + 2][r] + bv[ni + 2];
          ((u16*)C)[(size_t)m * N + n0 + wc * 64 + j]      = f2bf(v1 * cv - v2 * sv);
          ((u16*)C)[(size_t)m * N + n0 + wc * 64 + j + 32] = f2bf(v1 * sv + v2 * cv);
        }
      } else {
#pragma unroll
        for (int ni = 0; ni < 4; ++ni) {
          float v = acc[mi][ni][r] + bv[ni];
          size_t idx = (size_t)m * N + n0 + wc * 64 + ni * 16 + ln;
          if (OUT_BF16) ((u16*)C)[idx] = f2bf(v);
          else          ((float*)C)[idx] = v;
        }
      }
    }
  }
}

// ---------------------------------------------------------------- flash attention (causal)
// QBLK=64 (4 waves x 16 rows), KVBLK=128. K tile in LDS (swizzled, global_load_lds),
// V^T register-transpose staged, P via per-wave LDS slab. Descending-qt schedule.
__global__ __launch_bounds__(256) void flash2_kernel(const u16* __restrict__ Q, const u16* __restrict__ Kb,
                                                     const u16* __restrict__ V, u16* __restrict__ O) {
  __shared__ __align__(16) u16 lK[128 * 64];     // 16KB [k][d], chunk-swizzled c' = c ^ (k&7)
  __shared__ __align__(16) u16 vt[64 * 136];     // 17KB [d][k], chunk-swizzled c' = c ^ (d>>3)
  __shared__ __align__(16) u16 pl[4][16 * 136];  // 17KB per-wave P slab

  const int tid = threadIdx.x;
  const int w = tid >> 6, l = tid & 63, g = l >> 4, ln = l & 15;
  const int qt = 31 - blockIdx.x;                 // big blocks dispatch first
  const int bh = blockIdx.y;
  const int b = bh >> 4, h = bh & 15;
  const int q0 = qt * 64;
  const size_t rowbase = (size_t)b * T_SEQ * D_MOD + h * HEAD_DIM;

  short8 qf0, qf1;
  {
    const short8* qp = (const short8*)(Q + rowbase + (size_t)(q0 + w * 16 + ln) * D_MOD);
    qf0 = qp[g];
    qf1 = qp[4 + g];
  }
  floatx4 oacc[4];
#pragma unroll
  for (int nt = 0; nt < 4; ++nt) oacc[nt] = (floatx4){0.f, 0.f, 0.f, 0.f};
  float m_r[4] = {-INFINITY, -INFINITY, -INFINITY, -INFINITY};
  float l_r[4] = {0.f, 0.f, 0.f, 0.f};

  const int nkv = (qt >> 1) + 1;
  for (int kt = 0; kt < nkv; ++kt) {
    const int k0 = kt * 128;
    __syncthreads();   // previous iteration's vt/pl/lK readers done
    // ---- stage K tile via global_load_lds, source pre-swizzled so LDS chunk c holds global chunk c^(r&7)
#pragma unroll
    for (int p = 0; p < 4; ++p) {
      int c = p * 256 + w * 64 + l;
      int r = c >> 3, cc = c & 7;
      gload16(Kb + rowbase + (size_t)(k0 + r) * D_MOD + ((cc ^ (r & 7)) << 3),
              &lK[(p * 256 + w * 64) * 8]);
    }
    // ---- stage V^T (register transpose), conflict-free swizzled writes
#pragma unroll
    for (int p = 0; p < 4; ++p) {
      const int krow = (tid >> 3) + p * 32;
      const int d0 = (tid & 7) * 8;
      short8 vv = *(const short8*)(V + rowbase + (size_t)(k0 + krow) * D_MOD + d0);
#pragma unroll
      for (int i = 0; i < 8; ++i) {
        const int d = d0 + i;
        vt[d * 136 + (((krow >> 3) ^ (d >> 3)) << 3) + (krow & 7)] = (u16)vv[i];
      }
    }
    __syncthreads();   // K staged (vmcnt0) + vt written

    // ---- S = Q K^T from LDS
    float sv[8][4];
    const bool lastt = (kt == nkv - 1);
    __builtin_amdgcn_s_setprio(1);
#pragma unroll
    for (int nt = 0; nt < 8; ++nt) {
      const int n = nt * 16 + ln;
      short8 b0 = *(const short8*)&lK[n * 64 + ((g ^ (n & 7)) << 3)];
      short8 b1 = *(const short8*)&lK[n * 64 + (((4 + g) ^ (n & 7)) << 3)];
      floatx4 s = (floatx4){0.f, 0.f, 0.f, 0.f};
      s = mfma16(qf0, b0, s);
      s = mfma16(qf1, b1, s);
#pragma unroll
      for (int r = 0; r < 4; ++r) {
        float x = s[r] * 0.125f;
        if (lastt && (k0 + n) > (q0 + w * 16 + g * 4 + r)) x = -10000.0f;
        sv[nt][r] = x;
      }
    }
    __builtin_amdgcn_s_setprio(0);

    // ---- online softmax (rows in 16-lane groups)
#pragma unroll
    for (int r = 0; r < 4; ++r) {
      float mx = sv[0][r];
#pragma unroll
      for (int nt = 1; nt < 8; ++nt) mx = fmaxf(mx, sv[nt][r]);
      mx = fmaxf(mx, __shfl_xor(mx, 1));
      mx = fmaxf(mx, __shfl_xor(mx, 2));
      mx = fmaxf(mx, __shfl_xor(mx, 4));
      mx = fmaxf(mx, __shfl_xor(mx, 8));
      float mnew = fmaxf(m_r[r], mx);
      float alpha = __expf(m_r[r] - mnew);   // first tile: exp(-inf)=0
      float ssum = 0.f;
#pragma unroll
      for (int nt = 0; nt < 8; ++nt) {
        float pv = __expf(sv[nt][r] - mnew);
        sv[nt][r] = pv;
        ssum += pv;
      }
      ssum += __shfl_xor(ssum, 1);
      ssum += __shfl_xor(ssum, 2);
      ssum += __shfl_xor(ssum, 4);
      ssum += __shfl_xor(ssum, 8);
      l_r[r] = l_r[r] * alpha + ssum;
      m_r[r] = mnew;
#pragma unroll
      for (int nt = 0; nt < 4; ++nt) oacc[nt][r] *= alpha;
    }

    // ---- P -> bf16 -> LDS
    u16* pb = pl[w];
#pragma unroll
    for (int nt = 0; nt < 8; ++nt)
#pragma unroll
      for (int r = 0; r < 4; ++r)
        pb[(g * 4 + r) * 136 + nt * 16 + ln] = f2bf(sv[nt][r]);
    __syncthreads();   // P ready

    // ---- O += P V
    __builtin_amdgcn_s_setprio(1);
#pragma unroll
    for (int kk = 0; kk < 4; ++kk) {
      short8 pa = *(const short8*)&pb[ln * 136 + kk * 32 + g * 8];
#pragma unroll
      for (int nt = 0; nt < 4; ++nt) {
        const int d = nt * 16 + ln;
        const int kc = kk * 4 + g;
        short8 vb = *(const short8*)&vt[d * 136 + ((kc ^ (d >> 3)) << 3)];
        oacc[nt] = mfma16(pa, vb, oacc[nt]);
      }
    }
    __builtin_amdgcn_s_setprio(0);
  }

  // ---- epilogue
#pragma unroll
  for (int r = 0; r < 4; ++r) {
    float inv = 1.0f / l_r[r];
    const int q = q0 + w * 16 + g * 4 + r;
    u16* op = O + rowbase + (size_t)q * D_MOD;
#pragma unroll
    for (int nt = 0; nt < 4; ++nt)
      op[nt * 16 + ln] = f2bf(oacc[nt][r] * inv);
  }
}

// ---------------------------------------------------------------- launch
extern "C" void kernel_launch(void* const* d_in, const int* in_sizes, int n_in,
                              void* d_out, int out_size, void* d_ws, size_t ws_size,
                              hipStream_t stream) {
  const float* x  = (const float*)d_in[0];
  // d_in[1] = causal_mask (unused; causality computed analytically)
  const float* Wq = (const float*)d_in[2];
  const float* bq = (const float*)d_in[3];
  const float* Wk = (const float*)d_in[4];
  const float* bk = (const float*)d_in[5];
  const float* Wv = (const float*)d_in[6];
  const float* bv = (const float*)d_in[7];
  const float* Wo = (const float*)d_in[8];
  const float* bo = (const float*)d_in[9];
  float* out = (float*)d_out;

  char* ws = (char*)d_ws;
  const size_t MB = 1024 * 1024;
  u16* Xb   = (u16*)(ws + 0);          // 8 MB   [4096,1024] bf16
  u16* Wqb  = (u16*)(ws + 8 * MB);     // 2 MB each
  u16* Wkb  = (u16*)(ws + 10 * MB);
  u16* Wvb  = (u16*)(ws + 12 * MB);
  u16* Wob  = (u16*)(ws + 14 * MB);
  u16* Qb   = (u16*)(ws + 16 * MB);    // 8 MB each
  u16* Kb   = (u16*)(ws + 24 * MB);
  u16* Vb   = (u16*)(ws + 32 * MB);
  u16* Ab   = (u16*)(ws + 40 * MB);
  float* cosT = (float*)(ws + 48 * MB);          // 256 KB
  float* sinT = (float*)(ws + 48 * MB + 256 * 1024);

  cast_all_kernel<<<8192, 256, 0, stream>>>(x, Wq, Wk, Wv, Wo, Xb, Wqb, Wkb, Wvb, Wob);
  rope_table_kernel<<<256, 256, 0, stream>>>(cosT, sinT);

  // fused Q/K/V projections with RoPE in the Q/K epilogue
  gemm128_kernel<1, 1><<<dim3(8, 32, 3), 256, 0, stream>>>(
      Xb, Wqb, Wkb, Wvb, bq, bk, bv, Qb, Kb, Vb, cosT, sinT);

  flash2_kernel<<<dim3(32, 32), 256, 0, stream>>>(Qb, Kb, Vb, Ab);

  gemm128_kernel<0, 0><<<dim3(8, 32, 1), 256, 0, stream>>>(
      Ab, Wob, Wob, Wob, bo, bo, bo, out, out, out, nullptr, nullptr);
}